// Round 8
// baseline (568.419 us; speedup 1.0000x reference)
//
#include <hip/hip_runtime.h>

#define N_NODES 50000
#define N_EDGES 800000
#define D_IN    128
#define D_E     64
#define NH      4
#define F_TOT   128          // NH * D_OUT
#define NEG_SLOPE 0.2f

typedef __attribute__((ext_vector_type(8))) short short8;            // 8 bf16 (MFMA frag)
typedef __attribute__((ext_vector_type(8))) unsigned short ushort8;  // 8 bf16 (storage)
typedef __attribute__((ext_vector_type(4))) float f32x4;

__device__ __forceinline__ short f2bf(float x) {            // RNE f32->bf16
    unsigned u = __float_as_uint(x);
    u += 0x7FFFu + ((u >> 16) & 1u);
    return (short)(u >> 16);
}
__device__ __forceinline__ float b2f(unsigned short u) {    // bf16->f32 (1 shl)
    return __uint_as_float(((unsigned)u) << 16);
}
__device__ __forceinline__ int rfl(int x) {
    return __builtin_amdgcn_readfirstlane(x);
}

// ---------------------------------------------------------------------------
// HT16 row layout (256B/row, feature-permuted for fragment-contiguous gathers):
//   position p = g4*32 + ft*4 + r  <=>  feature f = ft*16 + g4*4 + r
//   => a k_fused lane (fixed g4) reads its 32 features as 64B contiguous.
// ---------------------------------------------------------------------------

// ---------------------------------------------------------------------------
// K1: fused hist + node transform (HT stored bf16-permuted; f32 HT deleted).
// ---------------------------------------------------------------------------
__global__ __launch_bounds__(256) void k_pre(
    const float* __restrict__ H, const float* __restrict__ W,
    unsigned short* __restrict__ HT16, const int* __restrict__ EI,
    int* __restrict__ deg)
{
    const int tid = threadIdx.x;
    for (int e = blockIdx.x * 256 + tid; e < N_EDGES; e += gridDim.x * 256)
        atomicAdd(&deg[EI[N_EDGES + e]], 1);

    __shared__ float wt[D_IN * F_TOT];   // wt[k*128+f] = W[f][k]
    for (int i = tid; i < D_IN * F_TOT; i += 256) {
        const int f = i & 127, k = i >> 7;
        wt[k * F_TOT + f] = W[f * D_IN + k];
    }
    __syncthreads();

    const int l = tid & 63;
    const int w = tid >> 6;
    const int gwave  = blockIdx.x * 4 + w;
    const int nwaves = gridDim.x * 4;
    const int ngroups = N_NODES / 8;     // 6250, exact

    // this lane owns features f=2l, 2l+1 (same ft,g4; r and r+1) -> one uint
    const int f_ = 2 * l;
    const int pos = (((f_ >> 2) & 3) * 32) + ((f_ >> 4) * 4) + (f_ & 3);

    for (int grp = gwave; grp < ngroups; grp += nwaves) {
        const int g = grp * 8;
        float ax[8], ay[8];
#pragma unroll
        for (int j = 0; j < 8; ++j) { ax[j] = 0.f; ay[j] = 0.f; }

        for (int k4 = 0; k4 < D_IN / 4; ++k4) {
            float hv[8][4];
#pragma unroll
            for (int j = 0; j < 8; ++j)
                *(float4*)hv[j] = *(const float4*)&H[(size_t)(g + j) * D_IN + k4 * 4];
#pragma unroll
            for (int kk = 0; kk < 4; ++kk) {
                const float2 wk = *(const float2*)&wt[(k4 * 4 + kk) * F_TOT + 2 * l];
#pragma unroll
                for (int j = 0; j < 8; ++j) {
                    ax[j] = fmaf(wk.x, hv[j][kk], ax[j]);
                    ay[j] = fmaf(wk.y, hv[j][kk], ay[j]);
                }
            }
        }
#pragma unroll
        for (int j = 0; j < 8; ++j) {
            const unsigned packed = (unsigned)(unsigned short)f2bf(ax[j])
                                  | ((unsigned)(unsigned short)f2bf(ay[j]) << 16);
            *(unsigned*)&HT16[(size_t)(g + j) * F_TOT + pos] = packed;
        }
    }
}

// ---------------------------------------------------------------------------
// K2: single-block exclusive scan (int4 + shfl second level)
// ---------------------------------------------------------------------------
__global__ __launch_bounds__(1024) void k_scan(
    const int* __restrict__ deg, int* __restrict__ row_start,
    int* __restrict__ cursor)
{
    __shared__ int wsum[16];
    __shared__ int carry;
    const int tid = threadIdx.x;
    const int l = tid & 63;
    const int wv = tid >> 6;
    if (tid == 0) carry = 0;

    const int4* deg4 = (const int4*)deg;
    const int N4 = N_NODES / 4;                 // 12500, exact

    for (int base = 0; base < N4; base += 1024) {
        __syncthreads();
        const int cb = carry;
        const int i4 = base + tid;
        int4 d = make_int4(0, 0, 0, 0);
        if (i4 < N4) d = deg4[i4];
        const int t0 = d.x, t1 = t0 + d.y, t2 = t1 + d.z, t3 = t2 + d.w;
        int x = t3;
#pragma unroll
        for (int off = 1; off < 64; off <<= 1) {
            int t = __shfl_up(x, off, 64);
            if (l >= off) x += t;
        }
        if (l == 63) wsum[wv] = x;
        __syncthreads();
        int s = (l < 16) ? wsum[l] : 0;
#pragma unroll
        for (int off = 1; off < 16; off <<= 1) {
            int t = __shfl_up(s, off, 64);
            if (l >= off) s += t;
        }
        const int tot      = __shfl(s, 15, 64);
        const int wave_off = (wv == 0) ? 0 : __shfl(s, wv - 1, 64);
        const int excl     = cb + wave_off + (x - t3);
        if (i4 < N4) {
            int4 rs;
            rs.x = excl; rs.y = excl + t0; rs.z = excl + t1; rs.w = excl + t2;
            ((int4*)row_start)[i4] = rs;
            ((int4*)cursor)[i4]    = rs;
        }
        if (tid == 0) carry = cb + tot;
    }
    __syncthreads();
    if (tid == 0) row_start[N_NODES] = carry;
}

// ---------------------------------------------------------------------------
// K3: CSR permutation build.
// ---------------------------------------------------------------------------
__global__ __launch_bounds__(256) void k_permute(
    const int* __restrict__ EI, int* __restrict__ cursor,
    int2* __restrict__ perm)
{
    const int e = blockIdx.x * 256 + threadIdx.x;
    if (e < N_EDGES) {
        const int src = EI[e];
        const int dst = EI[N_EDGES + e];
        const int pos = atomicAdd(&cursor[dst], 1);
        perm[pos] = make_int2(e, src);
    }
}

// ---------------------------------------------------------------------------
// K4: FUSED logits + aggregation, cross-node pipeline, R8:
//   - HT gathered as bf16 (halves the dominant 410MB stream; R7 evidence:
//     two designs both saturate ~4.9 TB/s mixed L2/L3/HBM service -> only
//     demand reduction moves the needle). Gather = 4x16B contiguous per lane
//     (permuted row layout). Converts via 1-op shl at consume.
//   - 4-deep cursor: E loads (the HBM stream, ~900cy) now issued 2 full
//     iterations ahead (evA/evB double buffer); hsv (L2/L3, ~500cy) 1-deep.
//   - budget: ev 32 + hsv(bf16) 16 + am 32 + misc ~25 ~= 105 < 128 cap.
// ---------------------------------------------------------------------------
__global__ __launch_bounds__(256, 2) void k_fused(
    const float* __restrict__ E, const float* __restrict__ We,
    const float* __restrict__ att, const unsigned short* __restrict__ HT16,
    const int2* __restrict__ perm, const int* __restrict__ row_start,
    float* __restrict__ out)
{
    __shared__ short8 s_bf[8][2][64];   // 16 KB: per-lane We fragments (bf16)
    __shared__ f32x4  s_att[8][4];      // 512 B
    __shared__ f32x4  s_hd[4][8][4];    // 2 KB: dst-row fragments, per wave

    const int tid = threadIdx.x;
    const int l   = tid & 63;
    const int wv  = tid >> 6;
    const int r16 = l & 15;          // edge slot within tile
    const int g4  = l >> 4;          // feature group / k-chunk selector

    if (wv == 0) {
#pragma unroll
        for (int ft = 0; ft < 8; ++ft) {
#pragma unroll
            for (int kc = 0; kc < 2; ++kc) {
                const float* wp = &We[(size_t)(ft * 16 + r16) * D_E + kc * 32 + g4 * 8];
                const f32x4 lo = *(const f32x4*)wp;
                const f32x4 hi = *(const f32x4*)(wp + 4);
                short8 b;
                b[0] = f2bf(lo[0]); b[1] = f2bf(lo[1]); b[2] = f2bf(lo[2]); b[3] = f2bf(lo[3]);
                b[4] = f2bf(hi[0]); b[5] = f2bf(hi[1]); b[6] = f2bf(hi[2]); b[7] = f2bf(hi[3]);
                s_bf[ft][kc][l] = b;
            }
        }
        if (l < 32) {
            const int ft = l >> 2, g = l & 3;
            s_att[ft][g] = *(const f32x4*)&att[ft * 16 + g * 4];
        }
    }
    __syncthreads();

    const int gs = rfl(gridDim.x * 4);

#define ADVP(NI, TI, EI_, NO, TO, EO)                                         \
    NO = NI;                                                                  \
    if ((TI) + 16 < (EI_)) { TO = (TI) + 16; EO = (EI_); }                    \
    else {                                                                    \
        NO = (NI) + gs;                                                       \
        if (NO < N_NODES) { TO = rfl(row_start[NO]); EO = rfl(row_start[NO + 1]); } \
        else { TO = 0; EO = 0; }                                              \
    }

    // ---- 4-deep cursor construction (wave-uniform scalars) ----
    int n0 = rfl(blockIdx.x * 4 + wv);
    int t0 = rfl(row_start[n0]);
    int e0 = rfl(row_start[n0 + 1]);
    int n1, t1, e1; ADVP(n0, t0, e0, n1, t1, e1);
    int n2, t2, e2; ADVP(n1, t1, e1, n2, t2, e2);
    int n3, t3, e3; ADVP(n2, t2, e2, n3, t3, e3);

    int nN = n3 + gs;                   // next-node preload
    int bN = 0, eN = 0;
    if (nN < N_NODES) { bN = rfl(row_start[nN]); eN = rfl(row_start[nN + 1]); }

#define PCLAMP(T, EE) (max(min((T) + r16, (EE) - 1), 0))

    // ---- pipeline prologue ----
    int2 pe0v = perm[PCLAMP(t0, e0)];
    int2 pe1v = perm[PCLAMP(t1, e1)];
    int2 pe2v = perm[PCLAMP(t2, e2)];
    int2 pe3v = perm[PCLAMP(t3, e3)];

    f32x4 evA0, evA1, evA2, evA3;       // c0's E row slice (in flight/arrived)
    f32x4 evB0, evB1, evB2, evB3;       // c1's E row slice (in flight)
    {
        const float* ep = &E[(size_t)pe0v.x * D_E + g4 * 8];
        evA0 = *(const f32x4*)ep;        evA1 = *(const f32x4*)(ep + 4);
        evA2 = *(const f32x4*)(ep + 32); evA3 = *(const f32x4*)(ep + 36);
    }
    {
        const float* ep = &E[(size_t)pe1v.x * D_E + g4 * 8];
        evB0 = *(const f32x4*)ep;        evB1 = *(const f32x4*)(ep + 4);
        evB2 = *(const f32x4*)(ep + 32); evB3 = *(const f32x4*)(ep + 36);
    }
    ushort8 hsv[4];                      // c0's HT16 gather (64B contiguous)
    {
        const unsigned short* hp = &HT16[(size_t)pe0v.y * F_TOT + g4 * 32];
        hsv[0] = *(const ushort8*)hp;        hsv[1] = *(const ushort8*)(hp + 8);
        hsv[2] = *(const ushort8*)(hp + 16); hsv[3] = *(const ushort8*)(hp + 24);
    }
    if (l < 16 && n0 < N_NODES) {
        const ushort8 h8 = *(const ushort8*)&HT16[(size_t)n0 * F_TOT + l * 8];
        f32x4 lo, hi;
#pragma unroll
        for (int r = 0; r < 4; ++r) { lo[r] = b2f(h8[r]); hi[r] = b2f(h8[4 + r]); }
        s_hd[wv][2 * (l & 3)][l >> 2]     = lo;
        s_hd[wv][2 * (l & 3) + 1][l >> 2] = hi;
    }

    f32x4 am[8];
#pragma unroll
    for (int ft = 0; ft < 8; ++ft) am[ft] = (f32x4){0.f, 0.f, 0.f, 0.f};
    float sw[4] = {0.f, 0.f, 0.f, 0.f};
    ushort8 hdld = (ushort8){0, 0, 0, 0, 0, 0, 0, 0};

    int safety = 65536;                 // hard bound: legit max ~50013
    while (n0 < N_NODES && safety-- > 0) {
        // A: advance c3; refresh next-node preload on crossing
        int n3n = n3, t3n = t3, e3n = e3;
        if (t3 + 16 < e3) { t3n = t3 + 16; }
        else if (n3 < N_NODES) {
            n3n = nN;
            if (nN < N_NODES) { t3n = bN; e3n = eN; } else { t3n = 0; e3n = 0; }
            nN += gs;
            if (nN < N_NODES) { bN = rfl(row_start[nN]); eN = rfl(row_start[nN + 1]); }
        }
        // B: issue perm for c3' (consumed 3 iterations from now)
        int2 peT = perm[PCLAMP(t3n, e3n)];
        // C: hd prefetch for n1's node (bf16, consumed next iteration)
        if (l < 16 && n1 < N_NODES)
            hdld = *(const ushort8*)&HT16[(size_t)n1 * F_TOT + l * 8];

        // D: conv evA -> af (evA issued 2 iterations ago)
        short8 af0, af1;
        af0[0]=f2bf(evA0[0]); af0[1]=f2bf(evA0[1]); af0[2]=f2bf(evA0[2]); af0[3]=f2bf(evA0[3]);
        af0[4]=f2bf(evA1[0]); af0[5]=f2bf(evA1[1]); af0[6]=f2bf(evA1[2]); af0[7]=f2bf(evA1[3]);
        af1[0]=f2bf(evA2[0]); af1[1]=f2bf(evA2[1]); af1[2]=f2bf(evA2[2]); af1[3]=f2bf(evA2[3]);
        af1[4]=f2bf(evA3[0]); af1[5]=f2bf(evA3[1]); af1[6]=f2bf(evA3[2]); af1[7]=f2bf(evA3[3]);
        // E: reissue evA for c2 (2-iteration flight time)
        {
            const float* ep = &E[(size_t)pe2v.x * D_E + g4 * 8];
            evA0 = *(const f32x4*)ep;        evA1 = *(const f32x4*)(ep + 4);
            evA2 = *(const f32x4*)(ep + 32); evA3 = *(const f32x4*)(ep + 36);
        }

        // F: MFMA + logit partial (hsv arrived: issued last iteration)
        float ph[4] = {0.f, 0.f, 0.f, 0.f};
#pragma unroll
        for (int ft = 0; ft < 8; ++ft) {
            f32x4 z = {0.f, 0.f, 0.f, 0.f};
            z = __builtin_amdgcn_mfma_f32_16x16x32_bf16(s_bf[ft][0][l], af0, z, 0, 0, 0);
            const f32x4 acc =
                __builtin_amdgcn_mfma_f32_16x16x32_bf16(s_bf[ft][1][l], af1, z, 0, 0, 0);
            const f32x4 at = s_att[ft][g4];
            const f32x4 hd = s_hd[wv][ft][g4];
            const ushort8 hc = hsv[ft >> 1];
            const int b = (ft & 1) * 4;
#pragma unroll
            for (int r = 0; r < 4; ++r) {
                float v = b2f(hc[b + r]) + hd[r] + acc[r];
                v = v > 0.f ? v : NEG_SLOPE * v;
                ph[ft >> 1] = fmaf(v, at[r], ph[ft >> 1]);
            }
        }
        // G: cross-lane logit reduce + softmax weight
        const bool valid = (t0 + r16) < e0;
#pragma unroll
        for (int h = 0; h < 4; ++h) {
            ph[h] += __shfl_xor(ph[h], 16, 64);
            ph[h] += __shfl_xor(ph[h], 32, 64);
        }
        float w[4];
#pragma unroll
        for (int h = 0; h < 4; ++h) {
            w[h] = valid ? __expf(ph[h]) : 0.f;
            sw[h] += w[h];
        }
        // H: message accumulation (last consumer of hsv; b2f rematerialized)
#pragma unroll
        for (int ft = 0; ft < 8; ++ft) {
            const ushort8 hc = hsv[ft >> 1];
            const int b = (ft & 1) * 4;
            const float wh = w[ft >> 1];
#pragma unroll
            for (int r = 0; r < 4; ++r)
                am[ft][r] = fmaf(wh, b2f(hc[b + r]), am[ft][r]);
        }
        // I: reissue hsv for c1
        {
            const unsigned short* hp = &HT16[(size_t)pe1v.y * F_TOT + g4 * 32];
            hsv[0] = *(const ushort8*)hp;        hsv[1] = *(const ushort8*)(hp + 8);
            hsv[2] = *(const ushort8*)(hp + 16); hsv[3] = *(const ushort8*)(hp + 24);
        }

        // J: node boundary — epilogue covers the just-issued loads
        if (n1 != n0) {
#pragma unroll
            for (int m = 1; m < 16; m <<= 1) {
#pragma unroll
                for (int h = 0; h < 4; ++h) sw[h] += __shfl_xor(sw[h], m, 64);
#pragma unroll
                for (int ft = 0; ft < 8; ++ft)
#pragma unroll
                    for (int r = 0; r < 4; ++r)
                        am[ft][r] += __shfl_xor(am[ft][r], m, 64);
            }
            float inv[4];
#pragma unroll
            for (int h = 0; h < 4; ++h) inv[h] = 1.f / (sw[h] + 1e-16f);
            if (r16 == 0) {
#pragma unroll
                for (int ft = 0; ft < 8; ++ft) {
                    f32x4 o;
#pragma unroll
                    for (int r = 0; r < 4; ++r) o[r] = am[ft][r] * inv[ft >> 1];
                    *(f32x4*)&out[(size_t)n0 * F_TOT + ft * 16 + g4 * 4] = o;
                }
            }
#pragma unroll
            for (int ft = 0; ft < 8; ++ft) am[ft] = (f32x4){0.f, 0.f, 0.f, 0.f};
            sw[0] = sw[1] = sw[2] = sw[3] = 0.f;
        }
        // s_hd update for n1 (after F read n0's copy; same-wave order, no barrier)
        if (l < 16) {
            f32x4 lo, hi;
#pragma unroll
            for (int r = 0; r < 4; ++r) { lo[r] = b2f(hdld[r]); hi[r] = b2f(hdld[4 + r]); }
            s_hd[wv][2 * (l & 3)][l >> 2]     = lo;
            s_hd[wv][2 * (l & 3) + 1][l >> 2] = hi;
        }

        // K: rotate cursors, perm registers, and ev double-buffer
        n0 = n1; t0 = t1; e0 = e1;
        n1 = n2; t1 = t2; e1 = e2;
        n2 = n3; t2 = t3; e2 = e3;
        n3 = n3n; t3 = t3n; e3 = e3n;
        pe1v = pe2v; pe2v = pe3v; pe3v = peT;
        f32x4 tv;
        tv = evA0; evA0 = evB0; evB0 = tv;
        tv = evA1; evA1 = evB1; evB1 = tv;
        tv = evA2; evA2 = evB2; evB2 = tv;
        tv = evA3; evA3 = evB3; evB3 = tv;
    }
#undef PCLAMP
#undef ADVP
}

extern "C" void kernel_launch(void* const* d_in, const int* in_sizes, int n_in,
                              void* d_out, int out_size, void* d_ws, size_t ws_size,
                              hipStream_t stream)
{
    const float* H   = (const float*)d_in[0];
    const int*   EI  = (const int*)d_in[1];
    const float* E   = (const float*)d_in[2];
    const float* W   = (const float*)d_in[3];
    const float* We  = (const float*)d_in[4];
    const float* att = (const float*)d_in[5];
    float* out = (float*)d_out;

    // workspace layout (~20 MB); all segments 16B-aligned
    unsigned short* HT16 = (unsigned short*)d_ws;               // 6.4M bf16 = 12.8 MB
    int2* perm      = (int2*)(HT16 + (size_t)N_NODES * F_TOT);  // 800k int2
    int*  deg       = (int*)(perm + N_EDGES);                   // 50k
    int*  row_start = deg + N_NODES;                            // 50004 (padded)
    int*  cursor    = row_start + N_NODES + 4;                  // 50k

    hipMemsetAsync(deg, 0, N_NODES * sizeof(int), stream);

    k_pre<<<512, 256, 0, stream>>>(H, W, HT16, EI, deg);
    k_scan<<<1, 1024, 0, stream>>>(deg, row_start, cursor);
    k_permute<<<(N_EDGES + 255) / 256, 256, 0, stream>>>(EI, cursor, perm);
    k_fused<<<1024, 256, 0, stream>>>(E, We, att, HT16, perm, row_start, out);
}